// Round 6
// baseline (1002.290 us; speedup 1.0000x reference)
//
#include <hip/hip_runtime.h>
#include <math.h>

#define NN 20000
#define EE 100000
#define FIN 167
#define KP1 256    // layer-1 K padded to mult of 64
#define HID 1024   // H*O = 4*256
#define OO 256
#define NB 16      // nodes per k_gath block

typedef unsigned short u16;
typedef short bf16x8 __attribute__((ext_vector_type(8)));
typedef short s16x4  __attribute__((ext_vector_type(4)));
typedef float f32x4  __attribute__((ext_vector_type(4)));

__device__ __forceinline__ float bf(u16 u){ return __uint_as_float(((unsigned)u)<<16); }
__device__ __forceinline__ u16 fb(float v){            // f32 -> bf16 RNE
  unsigned u = __float_as_uint(v);
  return (u16)((u + 0x7FFFu + ((u>>16)&1u)) >> 16);
}
__device__ __forceinline__ float ldv(const float* p, long i){ return p[i]; }
__device__ __forceinline__ float ldv(const u16*   p, long i){ return bf(p[i]); }

// ---------------- CSR build ----------------
__global__ void k_count(const int* __restrict__ ei, int* __restrict__ counts){
  int e = blockIdx.x*256 + threadIdx.x;
  if (e < EE) atomicAdd(&counts[ei[EE+e]], 1);
}

__global__ __launch_bounds__(256) void k_scan(const int* __restrict__ counts, int* __restrict__ iptr){
  __shared__ int sd[256];
  int tid = threadIdx.x;
  int carry = 0;
  for (int base=0; base<NN; base+=256){
    int i = base+tid;
    int v = (i<NN)? counts[i] : 0;
    sd[tid]=v;
    __syncthreads();
    for (int off=1; off<256; off<<=1){
      int t = (tid>=off)? sd[tid-off] : 0;
      __syncthreads();
      sd[tid] += t;
      __syncthreads();
    }
    if (i<NN) iptr[i] = carry + sd[tid] - v;
    carry += sd[255];
    __syncthreads();
  }
  if (tid==0) iptr[NN]=carry;
}

__global__ void k_fill(const int* __restrict__ ei, const int* __restrict__ iptr,
                       int* __restrict__ cursor, int* __restrict__ eid){
  int e = blockIdx.x*256 + threadIdx.x;
  if (e < EE){
    int d = ei[EE+e];
    int pos = atomicAdd(&cursor[d],1);
    eid[iptr[d]+pos] = e;
  }
}

// ---------------- BatchNorm stats ----------------
// layer-1 (float input, F=167): original coalesced version
template<typename T>
__global__ void k_bnstats(const T* __restrict__ X, float* __restrict__ sums, int F){
  int f = blockIdx.y*256 + threadIdx.x;
  if (f >= F) return;
  int r0 = blockIdx.x*100, r1 = r0+100;
  float s=0.f, s2=0.f;
  for (int r=r0;r<r1;r++){ float v = ldv(X,(long)r*F+f); s += v; s2 += v*v; }
  atomicAdd(&sums[f], s);
  atomicAdd(&sums[F+f], s2);
}

// layers 2/3 (bf16 input, F=HID): bf16x8-vectorized, LDS-combined atomics
__global__ __launch_bounds__(256) void k_bnstats8(const u16* __restrict__ X, float* __restrict__ sums){
  int tid = threadIdx.x;
  int f8 = (tid & 127)*8;
  int rbase = blockIdx.x*500;            // grid.x = 40, 500 rows/block
  float s[8]={0,0,0,0,0,0,0,0}, s2[8]={0,0,0,0,0,0,0,0};
  for (int r=rbase + (tid>>7); r<rbase+500; r+=2){
    bf16x8 v = *(const bf16x8*)(X + (long)r*HID + f8);
    #pragma unroll
    for (int j=0;j<8;j++){ float x=bf((u16)v[j]); s[j]+=x; s2[j]+=x*x; }
  }
  __shared__ float red[256][8];
  #pragma unroll
  for (int j=0;j<8;j++) red[tid][j]=s[j];
  __syncthreads();
  if (tid<128){
    #pragma unroll
    for (int j=0;j<8;j++) atomicAdd(&sums[f8+j], red[tid][j]+red[tid+128][j]);
  }
  __syncthreads();
  #pragma unroll
  for (int j=0;j<8;j++) red[tid][j]=s2[j];
  __syncthreads();
  if (tid<128){
    #pragma unroll
    for (int j=0;j<8;j++) atomicAdd(&sums[HID+f8+j], red[tid][j]+red[tid+128][j]);
  }
}

__global__ void k_bnfin(const float* __restrict__ sums, const float* __restrict__ g,
                        const float* __restrict__ b, float* __restrict__ scale,
                        float* __restrict__ shift, int F){
  int f = blockIdx.x*256 + threadIdx.x;
  if (f >= F) return;
  float mu  = sums[f]   * (1.f/NN);
  float var = sums[F+f] * (1.f/NN) - mu*mu;
  float sc  = rsqrtf(var + 1e-5f) * g[f];
  scale[f] = sc;
  shift[f] = b[f] - mu*sc;
}

// ---------------- BN-folded fused weight prep ----------------
__global__ __launch_bounds__(256) void k_foldT(const float* __restrict__ Wg, const float* __restrict__ Wl,
                        const float* __restrict__ scale,
                        u16* __restrict__ Wt, int K, int Kp){
  __shared__ float t[32][33];
  int k0 = blockIdx.x*32, c0 = blockIdx.y*32;
  int tx = threadIdx.x & 31, ty = threadIdx.x >> 5;
  bool second = (c0 >= HID);
  const float* W = second ? Wl : Wg;
  int cc0 = second ? c0 - HID : c0;
  #pragma unroll
  for (int i=0;i<4;i++){
    int k = k0 + ty + i*8;
    t[ty+i*8][tx] = (k < K) ? W[(long)k*HID + cc0 + tx] * scale[k] : 0.f;
  }
  __syncthreads();
  #pragma unroll
  for (int i=0;i<4;i++){
    int c = c0 + ty + i*8;
    Wt[(long)c*Kp + k0 + tx] = fb(t[tx][ty+i*8]);
  }
}

// cst init: lb for lin half, 0 for hg half
__global__ void k_cinit(const float* __restrict__ lb, float* __restrict__ cst){
  int c = blockIdx.x*256 + threadIdx.x;
  if (c < 2*HID) cst[c] = (c >= HID) ? lb[c-HID] : 0.f;
}

// cst[c] += sum_k shift[k]*W[k][c]  — parallel reduction, coalesced
__global__ __launch_bounds__(256) void k_const(const float* __restrict__ Wg, const float* __restrict__ Wl,
                        const float* __restrict__ shift, float* __restrict__ cst, int K){
  int tx = threadIdx.x & 63, ty = threadIdx.x >> 6;
  int c = blockIdx.x*64 + tx;
  bool second = c >= HID;
  const float* W = second ? Wl : Wg;
  int cc = second ? c-HID : c;
  int k0 = blockIdx.y*128;
  int k1 = min(K, k0+128);
  float s = 0.f;
  for (int k=k0+ty; k<k1; k+=4) s += shift[k]*W[(long)k*HID+cc];
  __shared__ float red[256];
  red[threadIdx.x] = s;
  __syncthreads();
  if (ty == 0){
    float tot = red[tx] + red[tx+64] + red[tx+128] + red[tx+192];
    atomicAdd(&cst[c], tot);
  }
}

__global__ void k_cast(const float* __restrict__ x, u16* __restrict__ xb){
  long idx = (long)blockIdx.x*256 + threadIdx.x;
  if (idx >= (long)NN*KP1) return;
  int n = (int)(idx / KP1), k = (int)(idx % KP1);
  xb[idx] = (k<FIN)? fb(x[(long)n*FIN+k]) : (u16)0;
}

__global__ void k_we16(const float* __restrict__ We, u16* __restrict__ We16){
  int i = blockIdx.x*256 + threadIdx.x;
  if (i < 10*HID) We16[i] = fb(We[i]);
}

// ---------------- MFMA GEMM (round-4 verified, FROZEN) ----------------
#define MF(a_,b_,c_) __builtin_amdgcn_mfma_f32_16x16x32_bf16(a_,b_,c_,0,0,0)
#define FENCE asm volatile("" ::: "memory")
#define BAR do { FENCE; __builtin_amdgcn_s_barrier(); FENCE; } while(0)

__global__ __launch_bounds__(512,2) void k_gemm(const u16* __restrict__ A, int K,
                     const u16* __restrict__ Wt, const float* __restrict__ cst,
                     u16* __restrict__ Chg, u16* __restrict__ Clin){
  __shared__ u16 lds[2][24576];   // [buf][Ak0|Ak1|Bk0|Bk1] = 16K+16K+8K+8K bytes, total 96 KB
  int b = blockIdx.x;
  int wg = (b & 7)*158 + (b >> 3);          // 1264 % 8 == 0 -> bijective XCD swizzle
  int row0 = (wg >> 4)*256, col0 = (wg & 15)*128;
  int tid = threadIdx.x;
  int wave = tid >> 6, lane = tid & 63, quad = lane >> 4, lo = lane & 15;
  int wm = wave >> 1, wn = wave & 1;        // 4 M-waves x 2 N-waves, 64x64 out each
  const u16* Apt[2];
  #pragma unroll
  for (int i=0;i<2;i++){
    int s = i*512 + tid, srow = s>>2;
    int gr = row0 + srow; if (gr >= NN) gr = NN-1;      // clamp: garbage rows never stored
    Apt[i] = A + (long)gr*K + (((s&3)^(srow&3))*8);
  }
  int brow = tid>>2;
  const u16* Bpt = Wt + (long)(col0 + brow)*K + ((((tid&3)^(brow&3)))*8);
  const char* ldsc = (const char*)&lds[0][0];
  int axor = lo & 3;
  int aoff = (wm*64 + lo)*64 + ((quad^axor)*16);
  int boff = 32768 + (wn*64 + lo)*64 + ((quad^axor)*16);
  int NT = K >> 6;
  f32x4 acc[4][4] = {};
  {
    u16* d = (u16*)&lds[0][0];
    __builtin_amdgcn_global_load_lds(Apt[0],      d +          tid*8, 16, 0, 0);
    __builtin_amdgcn_global_load_lds(Apt[1],      d +  4096 +  tid*8, 16, 0, 0);
    __builtin_amdgcn_global_load_lds(Bpt,         d + 16384 +  tid*8, 16, 0, 0);
    __builtin_amdgcn_global_load_lds(Apt[0] + 32, d +  8192 +  tid*8, 16, 0, 0);
    __builtin_amdgcn_global_load_lds(Apt[1] + 32, d + 12288 +  tid*8, 16, 0, 0);
    __builtin_amdgcn_global_load_lds(Bpt    + 32, d + 20480 +  tid*8, 16, 0, 0);
    asm volatile("s_waitcnt vmcnt(3)" ::: "memory");
    BAR;
  }
  for (int t=0; t<NT; t++){
    const char* Lb = ldsc + (t&1)*49152;
    u16* Sb = (u16*)&lds[0][0] + ((t&1)^1)*24576;
    int k0n = (t+1) << 6;
    int nx = (t+1 < NT);
    bf16x8 af[4], bfr[4];
    #pragma unroll
    for (int i=0;i<4;i++) af[i]  = *(const bf16x8*)(Lb + aoff + i*1024);
    #pragma unroll
    for (int n=0;n<4;n++) bfr[n] = *(const bf16x8*)(Lb + boff + n*1024);
    if (nx){
      __builtin_amdgcn_global_load_lds(Apt[0] + k0n, Sb +          tid*8, 16, 0, 0);
      __builtin_amdgcn_global_load_lds(Apt[1] + k0n, Sb +  4096 +  tid*8, 16, 0, 0);
      __builtin_amdgcn_global_load_lds(Bpt    + k0n, Sb + 16384 +  tid*8, 16, 0, 0);
    }
    #pragma unroll
    for (int i=0;i<4;i++)
      #pragma unroll
      for (int n=0;n<4;n++)
        acc[i][n] = MF(af[i], bfr[n], acc[i][n]);
    if (nx) asm volatile("s_waitcnt vmcnt(3)" ::: "memory");
    else    asm volatile("s_waitcnt vmcnt(0)" ::: "memory");
    BAR;
    #pragma unroll
    for (int i=0;i<4;i++) af[i]  = *(const bf16x8*)(Lb + 16384 + aoff + i*1024);
    #pragma unroll
    for (int n=0;n<4;n++) bfr[n] = *(const bf16x8*)(Lb +  8192 + boff + n*1024);
    if (nx){
      __builtin_amdgcn_global_load_lds(Apt[0] + k0n + 32, Sb +  8192 +  tid*8, 16, 0, 0);
      __builtin_amdgcn_global_load_lds(Apt[1] + k0n + 32, Sb + 12288 +  tid*8, 16, 0, 0);
      __builtin_amdgcn_global_load_lds(Bpt    + k0n + 32, Sb + 20480 +  tid*8, 16, 0, 0);
    }
    #pragma unroll
    for (int i=0;i<4;i++)
      #pragma unroll
      for (int n=0;n<4;n++)
        acc[i][n] = MF(af[i], bfr[n], acc[i][n]);
    if (nx) asm volatile("s_waitcnt vmcnt(3)" ::: "memory");
    BAR;
  }
  #pragma unroll
  for (int i=0;i<4;i++){
    #pragma unroll
    for (int n=0;n<4;n++){
      int col = col0 + wn*64 + n*16 + lo;
      float cs = cst[col];
      #pragma unroll
      for (int r=0;r<4;r++){
        int row = row0 + wm*64 + i*16 + quad*4 + r;   // C/D: col=lane&15, row=quad*4+reg
        if (row < NN){
          u16 o = fb(acc[i][n][r] + cs);
          if (col < HID) Chg[(long)row*HID + col] = o;
          else           Clin[(long)row*HID + col - HID] = o;
        }
      }
    }
  }
}
#undef MF
#undef BAR
#undef FENCE

// ---------------- per-(node,head) attention dots: wave-parallel, coalesced ----------------
__global__ __launch_bounds__(256) void k_sdot(const u16* __restrict__ hg, const float* __restrict__ attn,
                       float* __restrict__ ssrc, float* __restrict__ sdst){
  int unit = blockIdx.x*4 + (threadIdx.x >> 6);   // one wave per (n,h)
  if (unit >= NN*4) return;
  int lane = threadIdx.x & 63;
  int n = unit >> 2, h = unit & 3;
  const u16* hp = hg + (long)n*HID + h*OO + lane*4;
  s16x4 v = *(const s16x4*)hp;
  float4 x0 = *(const float4*)(attn + h*OO + lane*4);
  float4 x1 = *(const float4*)(attn + HID + h*OO + lane*4);
  float f0 = bf((u16)v.x), f1 = bf((u16)v.y), f2 = bf((u16)v.z), f3 = bf((u16)v.w);
  float ss = f0*x0.x + f1*x0.y + f2*x0.z + f3*x0.w;
  float sd = f0*x1.x + f1*x1.y + f2*x1.z + f3*x1.w;
  #pragma unroll
  for (int off=32; off>0; off>>=1){
    ss += __shfl_down(ss, off);
    sd += __shfl_down(sd, off);
  }
  if (lane==0){ ssrc[unit]=ss; sdst[unit]=sd; }
}

__global__ void k_q(const float* __restrict__ We, const float* __restrict__ attn,
                    float* __restrict__ q){
  int t = threadIdx.x;
  if (t >= 40) return;
  int k = t >> 2, h = t & 3;
  float s = 0.f;
  for (int d=0; d<OO; d++) s += We[(long)k*HID + h*OO + d] * attn[2*HID + h*OO + d];
  q[k*4+h] = s;
}

// per-EDGE logits: ea read once, all 4 heads computed, float4 write
__global__ void k_logits(const int* __restrict__ ei, const float* __restrict__ ea,
                         const float* __restrict__ q, const float* __restrict__ at,
                         const float* __restrict__ ssrc, const float* __restrict__ sdst,
                         float* __restrict__ L){
  int e = blockIdx.x*256 + threadIdx.x;
  if (e >= EE) return;
  int s = ei[e], dd = ei[EE+e];
  float4 a0 = *(const float4*)(ea + (long)e*12);
  float4 a1 = *(const float4*)(ea + (long)e*12 + 4);
  float4 a2 = *(const float4*)(ea + (long)e*12 + 8);
  float t = a0.x;
  float cc[10] = {a0.y,a0.z,a0.w, a1.x,a1.y,a1.z,a1.w, a2.x,a2.y,a2.z};
  float4 ss = *(const float4*)(ssrc + (long)s*4);
  float4 sd = *(const float4*)(sdst + (long)dd*4);
  float sv[4] = {ss.x+sd.x, ss.y+sd.y, ss.z+sd.z, ss.w+sd.w};
  float4 out;
  #pragma unroll
  for (int h=0;h<4;h++){
    float se = 0.f;
    #pragma unroll
    for (int k=0;k<10;k++) se += cc[k]*q[k*4+h];
    float v = sv[h] + se + t*at[h];
    ((float*)&out)[h] = (v>0.f)? v : 0.2f*v;
  }
  *(float4*)(L + (long)e*4) = out;
}

// per-NODE softmax finalize: writes w = exp(L-m)*dinv IN PLACE into L (float4),
// accumulates cw[n][4][10] with ea read ONCE per edge
__global__ void k_mden(const int* __restrict__ iptr, const int* __restrict__ eid,
                       const float* __restrict__ ea, float* __restrict__ L,
                       float* __restrict__ cw){
  int n = blockIdx.x*256 + threadIdx.x;
  if (n >= NN) return;
  int b = iptr[n], e1 = iptr[n+1];
  float m0=-INFINITY, m1=-INFINITY, m2=-INFINITY, m3=-INFINITY;
  for (int i=b;i<e1;i++){
    float4 l = *(const float4*)(L + (long)eid[i]*4);
    m0=fmaxf(m0,l.x); m1=fmaxf(m1,l.y); m2=fmaxf(m2,l.z); m3=fmaxf(m3,l.w);
  }
  if (b==e1){ m0=m1=m2=m3=0.f; }
  float s0=0.f,s1=0.f,s2=0.f,s3=0.f;
  for (int i=b;i<e1;i++){
    float4 l = *(const float4*)(L + (long)eid[i]*4);
    s0+=expf(l.x-m0); s1+=expf(l.y-m1); s2+=expf(l.z-m2); s3+=expf(l.w-m3);
  }
  float d0=1.f/(s0+1e-16f), d1=1.f/(s1+1e-16f), d2=1.f/(s2+1e-16f), d3=1.f/(s3+1e-16f);
  float c[4][10] = {};
  for (int i=b;i<e1;i++){
    int e = eid[i];
    float4 l = *(const float4*)(L + (long)e*4);
    float4 w = { expf(l.x-m0)*d0, expf(l.y-m1)*d1, expf(l.z-m2)*d2, expf(l.w-m3)*d3 };
    *(float4*)(L + (long)e*4) = w;
    float4 a0 = *(const float4*)(ea + (long)e*12);
    float4 a1 = *(const float4*)(ea + (long)e*12 + 4);
    float4 a2 = *(const float4*)(ea + (long)e*12 + 8);
    float cc[10] = {a0.y,a0.z,a0.w, a1.x,a1.y,a1.z,a1.w, a2.x,a2.y,a2.z};
    #pragma unroll
    for (int k=0;k<10;k++){
      c[0][k] += w.x*cc[k]; c[1][k] += w.y*cc[k];
      c[2][k] += w.z*cc[k]; c[3][k] += w.w*cc[k];
    }
  }
  float* cp = cw + (long)n*40;
  #pragma unroll
  for (int h=0;h<4;h++)
    #pragma unroll
    for (int k=0;k<10;k++) cp[h*10+k] = c[h][k];
}

// ---------------- edge gather: pure h[src] gather + per-node factored ew ----------------
__global__ __launch_bounds__(256) void k_gath(
    const u16* __restrict__ hg, const int* __restrict__ ei,
    const int* __restrict__ iptr, const int* __restrict__ eid,
    const float* __restrict__ L,      // holds w[e][h] (from k_mden)
    const float* __restrict__ cw,     // [NN][4][10]
    const u16* __restrict__ We16, const float* __restrict__ cb,
    u16* __restrict__ lio)
{
  __shared__ u16  sWe[10*HID];   // 20 KB
  __shared__ float scb[HID];     // 4 KB
  int tid = threadIdx.x;
  for (int i=tid;i<10*HID;i+=256) sWe[i] = We16[i];
  for (int i=tid;i<HID;i+=256) scb[i] = cb[i];
  __syncthreads();
  int d0 = blockIdx.x*NB, dend = min(NN, d0+NB);
  for (int d=d0; d<dend; d++){
    float acc[4];
    #pragma unroll
    for (int j=0;j<4;j++) acc[j] = bf(lio[(long)d*HID + tid + j*256]);
    int b0 = iptr[d], en = iptr[d+1];
    for (int i=b0;i<en;i++){
      int e = eid[i], s_ = ei[e];
      float4 w4 = *(const float4*)(L + (long)e*4);   // broadcast
      const u16* hgs = hg + (long)s_*HID + tid;
      acc[0] += w4.x*bf(hgs[0]);
      acc[1] += w4.y*bf(hgs[256]);
      acc[2] += w4.z*bf(hgs[512]);
      acc[3] += w4.w*bf(hgs[768]);
    }
    const float* cp = cw + (long)d*40;
    #pragma unroll
    for (int j=0;j<4;j++){
      float ew = 0.f;
      #pragma unroll
      for (int k=0;k<10;k++) ew += cp[j*10+k]*bf(sWe[k*HID + tid + j*256]);
      acc[j] += ew;
    }
    #pragma unroll
    for (int j=0;j<4;j++){
      int f = tid + j*256;
      lio[(long)d*HID+f] = fb(fmaxf(acc[j] + scb[f], 0.f));
    }
  }
}

// ---------------- layer 3 ----------------
__global__ void k_c4init(const float* __restrict__ lb, float* __restrict__ c4){
  if (threadIdx.x==0 && blockIdx.x==0){ c4[0]=0.f; c4[1]=0.f; c4[2]=lb[0]; c4[3]=lb[1]; }
}

// fold BN scale into interleaved weights W4[k][4] = {Wg0,Wg1,lw0,lw1}*sc; shift -> c4
__global__ __launch_bounds__(256) void k_fold3(const float* __restrict__ Wg, const float* __restrict__ lw,
                        const float* __restrict__ scale, const float* __restrict__ shift,
                        float* __restrict__ W4, float* __restrict__ c4){
  int k = blockIdx.x*256 + threadIdx.x;   // grid 4, covers HID exactly
  float sc = scale[k], sh = shift[k];
  float w0=Wg[k*2], w1=Wg[k*2+1], l0=lw[k*2], l1=lw[k*2+1];
  float4 o = {w0*sc, w1*sc, l0*sc, l1*sc};
  *(float4*)(W4 + (long)k*4) = o;
  __shared__ float red[256][4];
  int tid = threadIdx.x;
  red[tid][0]=sh*w0; red[tid][1]=sh*w1; red[tid][2]=sh*l0; red[tid][3]=sh*l1;
  __syncthreads();
  for (int o2=128;o2>0;o2>>=1){
    if (tid<o2){
      #pragma unroll
      for (int j=0;j<4;j++) red[tid][j]+=red[tid+o2][j];
    }
    __syncthreads();
  }
  if (tid==0){
    #pragma unroll
    for (int j=0;j<4;j++) atomicAdd(&c4[j], red[0][j]);
  }
}

// wave-per-node GEMV: x-rows and W4 staged in LDS, shuffle reduce, no post-stage barriers
__global__ __launch_bounds__(256) void k_n3(const u16* __restrict__ in,
    const float* __restrict__ W4, const float* __restrict__ c4,
    const float* __restrict__ attn,
    float* __restrict__ hg3, float* __restrict__ lin3,
    float* __restrict__ ssrc, float* __restrict__ sdst)
{
  __shared__ float sW[HID*4];   // 16 KB
  __shared__ float sx[4][HID];  // 16 KB
  int tid = threadIdx.x;
  int n0 = blockIdx.x*4;        // grid 5000 exact
  for (int i=tid; i<HID; i+=256) *(float4*)&sW[i*4] = *(const float4*)(W4 + (long)i*4);
  for (int idx=tid; idx<512; idx+=256){
    int rr = idx>>7, ch = idx&127;
    bf16x8 v = *(const bf16x8*)(in + (long)(n0+rr)*HID + ch*8);
    #pragma unroll
    for (int j=0;j<8;j++) sx[rr][ch*8+j] = bf((u16)v[j]);
  }
  __syncthreads();
  int w = tid>>6, lane = tid&63;
  float p0=0.f,p1=0.f,p2=0.f,p3=0.f;
  #pragma unroll
  for (int g=0; g<16; g++){
    int k = g*64 + lane;                      // lanes consecutive -> conflict-free
    float x = sx[w][k];
    float4 wv = *(const float4*)&sW[k*4];
    p0 += x*wv.x; p1 += x*wv.y; p2 += x*wv.z; p3 += x*wv.w;
  }
  #pragma unroll
  for (int off=32; off>0; off>>=1){
    p0 += __shfl_down(p0, off);
    p1 += __shfl_down(p1, off);
    p2 += __shfl_down(p2, off);
    p3 += __shfl_down(p3, off);
  }
  if (lane==0){
    int n = n0 + w;
    float r0=p0+c4[0], r1=p1+c4[1], r2=p2+c4[2], r3=p3+c4[3];
    hg3[n*2]=r0; hg3[n*2+1]=r1;
    lin3[n*2]=r2; lin3[n*2+1]=r3;
    ssrc[n]=r0*attn[0]+r1*attn[1];
    sdst[n]=r0*attn[2]+r1*attn[3];
  }
}

__global__ void k_logits3(const int* __restrict__ ei, const float* __restrict__ ea,
                          const float* __restrict__ We, const float* __restrict__ attn,
                          const float* __restrict__ at, const float* __restrict__ ssrc,
                          const float* __restrict__ sdst, float* __restrict__ L){
  int e = blockIdx.x*256 + threadIdx.x;
  if (e >= EE) return;
  int s = ei[e], d = ei[EE+e];
  float e0=0.f, e1=0.f;
  #pragma unroll
  for (int k=0;k<10;k++){
    float c = ea[e*12+1+k];
    e0 += c*We[k*2]; e1 += c*We[k*2+1];
  }
  float se = e0*attn[4] + e1*attn[5];
  float v = ssrc[s] + sdst[d] + se + ea[e*12]*at[0];
  L[e] = (v>0.f)? v : 0.2f*v;
}

// layer-3 softmax finalize: w in place + cw3[n][k]
__global__ void k_mden3(const int* __restrict__ iptr, const int* __restrict__ eid,
                        const float* __restrict__ ea, float* __restrict__ L,
                        float* __restrict__ cw){
  int n = blockIdx.x*256 + threadIdx.x;
  if (n >= NN) return;
  int b = iptr[n], e1 = iptr[n+1];
  float mx = -INFINITY;
  for (int i=b;i<e1;i++) mx = fmaxf(mx, L[eid[i]]);
  if (b == e1) mx = 0.f;
  float s = 0.f;
  for (int i=b;i<e1;i++) s += expf(L[eid[i]] - mx);
  float dv = 1.f/(s+1e-16f);
  float c[10] = {0.f,0.f,0.f,0.f,0.f,0.f,0.f,0.f,0.f,0.f};
  for (int i=b;i<e1;i++){
    int e = eid[i];
    float w = expf(L[e]-mx)*dv;
    L[e] = w;
    #pragma unroll
    for (int k=0;k<10;k++) c[k] += w*ea[e*12+1+k];
  }
  float* cp = cw + (long)n*10;
  #pragma unroll
  for (int k=0;k<10;k++) cp[k] = c[k];
}

__global__ void k_gather3(const int* __restrict__ ei,
                          const int* __restrict__ iptr, const int* __restrict__ eid,
                          const float* __restrict__ L,      // holds w[e]
                          const float* __restrict__ cw,     // [NN][10]
                          const float* __restrict__ hg3,
                          const float* __restrict__ We, const float* __restrict__ lin3,
                          const float* __restrict__ cb, float* __restrict__ out){
  int n = blockIdx.x*256 + threadIdx.x;
  if (n >= NN) return;
  int b = iptr[n], en = iptr[n+1];
  const float* cp = cw + (long)n*10;
  float e0f=0.f, e1f=0.f;
  #pragma unroll
  for (int k=0;k<10;k++){ e0f += cp[k]*We[k*2]; e1f += cp[k]*We[k*2+1]; }
  float a0=0.f, a1=0.f;
  for (int i=b;i<en;i++){
    int e = eid[i], s_ = ei[e];
    float w = L[e];
    a0 += w*hg3[s_*2];
    a1 += w*hg3[s_*2+1];
  }
  out[n*2]   = fmaxf(lin3[n*2]  +a0+e0f+cb[0], 0.f);
  out[n*2+1] = fmaxf(lin3[n*2+1]+a1+e1f+cb[1], 0.f);
}

extern "C" void kernel_launch(void* const* d_in, const int* in_sizes, int n_in,
                              void* d_out, int out_size, void* d_ws, size_t ws_size,
                              hipStream_t stream){
  const int* ei = (const int*)d_in[1];

  long long sz[64];
  {
    const long long* s64 = (const long long*)(const void*)in_sizes;
    bool is64 = (n_in >= 2) && (in_sizes[0] == 3340000) && (in_sizes[1] == 0)
                && (s64[1] == 200000);
    for (int i=0;i<n_in && i<64;i++) sz[i] = is64 ? s64[i] : (long long)in_sizes[i];
  }

  int IWg[3], IWe[3], IAttn[3], IAt[3], ICb[3], ILw[3], ILb[3], IG[3], IB[3];
  if (n_in > 8 && sz[8] == (long long)HID*HID){ // setup_inputs() dict order
    for (int l=0;l<3;l++){
      IWg[l]=3+l*5; IWe[l]=4+l*5; IAttn[l]=5+l*5; IAt[l]=6+l*5; ICb[l]=7+l*5;
      ILw[l]=18+l*4; ILb[l]=19+l*4; IG[l]=20+l*4; IB[l]=21+l*4;
    }
  } else {
    int idx=3;
    for (int l=0;l<3;l++){
      IWg[l]=idx++; IWe[l]=idx++; IAttn[l]=idx++; IAt[l]=idx++; ICb[l]=idx++;
      ILw[l]=idx++; ILb[l]=idx++; IG[l]=idx++; IB[l]=idx++;
    }
  }
  #define FP(i) ((const float*)d_in[(i)])

  char* ws = (char*)d_ws;
  size_t off = 0;
  auto alloc = [&](size_t bytes)->void*{ void* p = ws + off; off += (bytes + 255) & ~(size_t)255; return p; };
  auto G = [](long n){ return (int)((n+255)/256); };

  u16*   buf0 = (u16*)  alloc((size_t)NN*HID*2);   // hg (bf16)
  u16*   bufA = (u16*)  alloc((size_t)NN*HID*2);   // layer-1 lin/result
  u16*   bufB = (u16*)  alloc((size_t)NN*HID*2);   // layer-2 lin/result
  u16*   xbf  = (u16*)  alloc((size_t)NN*KP1*2);   // layer-1 A (bf16, padded)
  u16*   Wt   = (u16*)  alloc((size_t)2*HID*HID*2);// fused folded weights [2048][K] K-major
  u16*   We16 = (u16*)  alloc((size_t)10*HID*2);
  float* cst  = (float*)alloc(2*HID*4);
  float* L    = (float*)alloc((size_t)EE*4*4);
  float* ssrc = (float*)alloc((size_t)NN*4*4);
  float* sdst = (float*)alloc((size_t)NN*4*4);
  int*   iptr = (int*)  alloc((size_t)(NN+4)*4);
  int*   cnts = (int*)  alloc((size_t)NN*4);
  int*   eid  = (int*)  alloc((size_t)EE*4);
  float* stats= (float*)alloc(2*HID*4);
  float* scale= (float*)alloc(HID*4);
  float* shift= (float*)alloc(HID*4);
  float* qbuf = (float*)alloc(64*4);
  float* hg3  = (float*)alloc((size_t)NN*2*4);
  float* lin3 = (float*)alloc((size_t)NN*2*4);
  float* cw   = (float*)alloc((size_t)NN*40*4);    // factored edge-feature weights
  float* W4   = (float*)alloc((size_t)HID*4*4);    // layer-3 folded interleaved weights
  float* c4   = (float*)alloc(4*4);

  // ---- CSR by dst ----
  hipMemsetAsync(cnts, 0, NN*sizeof(int), stream);
  k_count<<<G(EE),256,0,stream>>>(ei, cnts);
  k_scan<<<1,256,0,stream>>>(cnts, iptr);
  hipMemsetAsync(cnts, 0, NN*sizeof(int), stream);
  k_fill<<<G(EE),256,0,stream>>>(ei, iptr, cnts, eid);

  int gg = 1264;   // 79 row-tiles (256 rows) x 16 col-tiles (128 cols), XCD-swizzled in-kernel
  int gsd = (NN*4+3)/4;   // k_sdot: one wave per (n,h)

  // ---- layer 1 (A = bf16(x), Kp=256) ----
  {
    hipMemsetAsync(stats, 0, 2*FIN*sizeof(float), stream);
    dim3 bg(200, 1);
    k_bnstats<float><<<bg,256,0,stream>>>(FP(0), stats, FIN);
    k_bnfin<<<1,256,0,stream>>>(stats, FP(IG[0]), FP(IB[0]), scale, shift, FIN);
    k_cast<<<G((long)NN*KP1),256,0,stream>>>(FP(0), xbf);
    dim3 ft(KP1/32, 64);
    k_foldT<<<ft,256,0,stream>>>(FP(IWg[0]), FP(ILw[0]), scale, Wt, FIN, KP1);
    k_cinit<<<8,256,0,stream>>>(FP(ILb[0]), cst);
    dim3 cg(32, (FIN+127)/128);
    k_const<<<cg,256,0,stream>>>(FP(IWg[0]), FP(ILw[0]), shift, cst, FIN);
    k_we16<<<40,256,0,stream>>>(FP(IWe[0]), We16);
    k_gemm<<<gg,512,0,stream>>>(xbf, KP1, Wt, cst, buf0, bufA);
    k_sdot<<<gsd,256,0,stream>>>(buf0, FP(IAttn[0]), ssrc, sdst);
    k_q<<<1,64,0,stream>>>(FP(IWe[0]), FP(IAttn[0]), qbuf);
    k_logits<<<G(EE),256,0,stream>>>(ei, FP(2), qbuf, FP(IAt[0]), ssrc, sdst, L);
    k_mden<<<G(NN),256,0,stream>>>(iptr, eid, FP(2), L, cw);
    k_gath<<<(NN+NB-1)/NB,256,0,stream>>>(buf0, ei, iptr, eid, L, cw,
                                          We16, FP(ICb[0]), bufA);
  }
  // ---- layer 2 (A = bufA, K=1024) ----
  {
    hipMemsetAsync(stats, 0, 2*HID*sizeof(float), stream);
    k_bnstats8<<<40,256,0,stream>>>(bufA, stats);
    k_bnfin<<<4,256,0,stream>>>(stats, FP(IG[1]), FP(IB[1]), scale, shift, HID);
    dim3 ft(HID/32, 64);
    k_foldT<<<ft,256,0,stream>>>(FP(IWg[1]), FP(ILw[1]), scale, Wt, HID, HID);
    k_cinit<<<8,256,0,stream>>>(FP(ILb[1]), cst);
    dim3 cg(32, HID/128);
    k_const<<<cg,256,0,stream>>>(FP(IWg[1]), FP(ILw[1]), shift, cst, HID);
    k_we16<<<40,256,0,stream>>>(FP(IWe[1]), We16);
    k_gemm<<<gg,512,0,stream>>>(bufA, HID, Wt, cst, buf0, bufB);
    k_sdot<<<gsd,256,0,stream>>>(buf0, FP(IAttn[1]), ssrc, sdst);
    k_q<<<1,64,0,stream>>>(FP(IWe[1]), FP(IAttn[1]), qbuf);
    k_logits<<<G(EE),256,0,stream>>>(ei, FP(2), qbuf, FP(IAt[1]), ssrc, sdst, L);
    k_mden<<<G(NN),256,0,stream>>>(iptr, eid, FP(2), L, cw);
    k_gath<<<(NN+NB-1)/NB,256,0,stream>>>(buf0, ei, iptr, eid, L, cw,
                                          We16, FP(ICb[1]), bufB);
  }

  // ---- layer 3 (input = bufB) ----
  hipMemsetAsync(stats, 0, 2*HID*sizeof(float), stream);
  k_bnstats8<<<40,256,0,stream>>>(bufB, stats);
  k_bnfin<<<4,256,0,stream>>>(stats, FP(IG[2]), FP(IB[2]), scale, shift, HID);
  k_c4init<<<1,64,0,stream>>>(FP(ILb[2]), c4);
  k_fold3<<<HID/256,256,0,stream>>>(FP(IWg[2]), FP(ILw[2]), scale, shift, W4, c4);
  k_n3<<<NN/4,256,0,stream>>>(bufB, W4, c4, FP(IAttn[2]), hg3, lin3, ssrc, sdst);
  k_logits3<<<G(EE),256,0,stream>>>(ei, FP(2), FP(IWe[2]), FP(IAttn[2]), FP(IAt[2]), ssrc, sdst, L);
  k_mden3<<<G(NN),256,0,stream>>>(iptr, eid, FP(2), L, cw);
  k_gather3<<<G(NN),256,0,stream>>>(ei, iptr, eid, L, cw, hg3,
                                    FP(IWe[2]), lin3, FP(ICb[2]), (float*)d_out);
}